// Round 6
// baseline (434.789 us; speedup 1.0000x reference)
//
#include <hip/hip_runtime.h>
#include <hip/hip_bf16.h>

// Problem constants (from reference)
#define NN 50000
#define EE 800000
#define INF_ 128
#define HH 4
#define FF 32
#define HF 128          // H*F
#define OUTC 160        // (H+1)*F per node
#define NEG_SLOPE 0.2f

#define SCAN_B 196      // ceil(50000/256)

typedef __attribute__((ext_vector_type(8))) short short8;
typedef __attribute__((ext_vector_type(4))) float f32x4;

// fp32 -> bf16 bits, round-to-nearest-even
__device__ __forceinline__ unsigned short f2bf(float f) {
    union { float f; unsigned u; } in; in.f = f;
    unsigned u = in.u;
    u += 0x7fffu + ((u >> 16) & 1u);
    return (unsigned short)(u >> 16);
}
__device__ __forceinline__ float bflo(unsigned w) {   // low ushort as bf16 -> f32
    return __uint_as_float(w << 16);
}
__device__ __forceinline__ float bfhi(unsigned w) {   // high ushort as bf16 -> f32
    return __uint_as_float(w & 0xffff0000u);
}
__device__ __forceinline__ float bf1(unsigned short w) {
    return __uint_as_float((unsigned)w << 16);
}

// ---------------- CSR build ----------------
__global__ void zero_counts(int* __restrict__ counts) {
    int idx = blockIdx.x * blockDim.x + threadIdx.x;
    if (idx < NN) counts[idx] = 0;
}

// histogram; atomic return value = rank of edge within its dst bucket
__global__ void hist_kernel(const int* __restrict__ dst, int* __restrict__ counts,
                            int* __restrict__ rank) {
    int e = blockIdx.x * blockDim.x + threadIdx.x;
    if (e < EE) rank[e] = atomicAdd(&counts[dst[e]], 1);
}

// phase 1: per-block sum of 256 counts
__global__ __launch_bounds__(256) void scan_bsum(
    const int* __restrict__ counts, int* __restrict__ bsum)
{
    __shared__ int sh[256];
    int t = threadIdx.x;
    int idx = blockIdx.x * 256 + t;
    sh[t] = (idx < NN) ? counts[idx] : 0;
    __syncthreads();
    #pragma unroll
    for (int off = 128; off > 0; off >>= 1) {
        if (t < off) sh[t] += sh[t + off];
        __syncthreads();
    }
    if (t == 0) bsum[blockIdx.x] = sh[0];
}

// phase 2: single-block exclusive scan of SCAN_B partials
__global__ __launch_bounds__(256) void scan_top(
    const int* __restrict__ bsum, int* __restrict__ bprefix)
{
    __shared__ int sh[256];
    int t = threadIdx.x;
    int v = (t < SCAN_B) ? bsum[t] : 0;
    sh[t] = v;
    __syncthreads();
    #pragma unroll
    for (int off = 1; off < 256; off <<= 1) {
        int u = (t >= off) ? sh[t - off] : 0;
        __syncthreads();
        sh[t] += u;
        __syncthreads();
    }
    if (t < SCAN_B) bprefix[t] = sh[t] - v;   // exclusive
}

// phase 3: per-block exclusive scan + block prefix -> offsets
__global__ __launch_bounds__(256) void scan_final(
    const int* __restrict__ counts, const int* __restrict__ bprefix,
    int* __restrict__ offsets)
{
    __shared__ int sh[256];
    int t = threadIdx.x;
    int idx = blockIdx.x * 256 + t;
    int v = (idx < NN) ? counts[idx] : 0;
    sh[t] = v;
    __syncthreads();
    #pragma unroll
    for (int off = 1; off < 256; off <<= 1) {
        int u = (t >= off) ? sh[t - off] : 0;
        __syncthreads();
        sh[t] += u;
        __syncthreads();
    }
    if (idx < NN) offsets[idx] = sh[t] - v + bprefix[blockIdx.x];
}

// atomic-free scatter using precomputed ranks
__global__ void scatter_kernel(const int* __restrict__ src, const int* __restrict__ dst,
                               const int* __restrict__ offsets, const int* __restrict__ rank,
                               int* __restrict__ srcbuck)
{
    int e = blockIdx.x * blockDim.x + threadIdx.x;
    if (e < EE) srcbuck[offsets[dst[e]] + rank[e]] = src[e];
}

// ---------------- weight prep: concat + transpose + bf16 ----------------
__global__ __launch_bounds__(256) void prep_weights(
    const float* __restrict__ W0, const float* __restrict__ b0,
    const float* __restrict__ W1, const float* __restrict__ b1,
    const float* __restrict__ W2, const float* __restrict__ b2,
    const float* __restrict__ W3, const float* __restrict__ b3,
    unsigned short* __restrict__ WbT, float* __restrict__ biasc)
{
    int idx = blockIdx.x * 256 + threadIdx.x;   // 416*128 = 53248
    if (idx >= 416 * 128) return;
    int n = idx >> 7, k = idx & 127;
    float v;
    if (n < 128)      v = W0[k * 128 + n];
    else if (n < 256) v = W1[k * 128 + (n - 128)];
    else if (n < 384) v = W2[k * 128 + (n - 256)];
    else              v = W3[k * 32  + (n - 384)];
    WbT[n * 128 + k] = f2bf(v);
    if (idx < 416) {
        float bv;
        if (idx < 128)      bv = b0[idx];
        else if (idx < 256) bv = b1[idx - 128];
        else if (idx < 384) bv = b2[idx - 256];
        else                bv = b3[idx - 384];
        biasc[idx] = bv;
    }
}

// ---------------- bf16 MFMA projection GEMM ----------------
// epilogue: cols 0-127 -> elm bf16, 128-255 -> er_mut fp32,
//           256-383 -> els bf16, 384-415 -> out feat_lin
#define LSTRIDE 136
__global__ __launch_bounds__(256) void proj_gemm_mfma(
    const float* __restrict__ feat,
    const unsigned short* __restrict__ WbT,
    const float* __restrict__ biasc,
    unsigned short* __restrict__ elm, unsigned short* __restrict__ els,
    float* __restrict__ er_mut, float* __restrict__ out)
{
    __shared__ unsigned short As[64  * LSTRIDE];
    __shared__ unsigned short Bs[208 * LSTRIDE];

    const int tid  = threadIdx.x;
    const int row0 = blockIdx.x * 64;
    const int nbase = blockIdx.y * 208;

    #pragma unroll
    for (int it = 0; it < 8; ++it) {
        int f  = tid + it * 256;
        int r  = f >> 5;
        int k4 = f & 31;
        int grow = row0 + r;
        float4 v = make_float4(0.f, 0.f, 0.f, 0.f);
        if (grow < NN) v = ((const float4*)feat)[(size_t)grow * 32 + k4];
        unsigned p0 = (unsigned)f2bf(v.x) | ((unsigned)f2bf(v.y) << 16);
        unsigned p1 = (unsigned)f2bf(v.z) | ((unsigned)f2bf(v.w) << 16);
        uint2 pk; pk.x = p0; pk.y = p1;
        *(uint2*)&As[r * LSTRIDE + k4 * 4] = pk;
    }
    #pragma unroll
    for (int it = 0; it < 26; ++it) {
        int c  = tid + it * 256;
        int n  = c >> 5;
        int kc = c & 31;
        uint2 v = *(const uint2*)&WbT[(size_t)(nbase + n) * 128 + kc * 4];
        *(uint2*)&Bs[n * LSTRIDE + kc * 4] = v;
    }
    __syncthreads();

    const int wv   = tid >> 6;
    const int lane = tid & 63;
    const int m16  = lane & 15;
    const int quad = lane >> 4;

    f32x4 acc[13];
    #pragma unroll
    for (int t = 0; t < 13; ++t) acc[t] = (f32x4){0.f, 0.f, 0.f, 0.f};

    short8 afr[4];
    const unsigned short* Abase = &As[(wv * 16 + m16) * LSTRIDE + quad * 8];
    #pragma unroll
    for (int ks = 0; ks < 4; ++ks)
        afr[ks] = *(const short8*)(Abase + ks * 32);

    #pragma unroll
    for (int t = 0; t < 13; ++t) {
        const unsigned short* Bbase = &Bs[(t * 16 + m16) * LSTRIDE + quad * 8];
        #pragma unroll
        for (int ks = 0; ks < 4; ++ks) {
            short8 bfr = *(const short8*)(Bbase + ks * 32);
            acc[t] = __builtin_amdgcn_mfma_f32_16x16x32_bf16(afr[ks], bfr, acc[t], 0, 0, 0);
        }
    }

    #pragma unroll
    for (int t = 0; t < 13; ++t) {
        int col = nbase + t * 16 + m16;
        float bb = biasc[col];
        #pragma unroll
        for (int r = 0; r < 4; ++r) {
            int grow = row0 + wv * 16 + quad * 4 + r;
            if (grow >= NN) continue;
            float v = acc[t][r] + bb;
            if (col < 128)      elm[(size_t)grow * HF + col] = f2bf(v);
            else if (col < 256) er_mut[(size_t)grow * HF + (col - 128)] = v;
            else if (col < 384) els[(size_t)grow * HF + (col - 256)] = f2bf(v);
            else                out[(size_t)grow * OUTC + (col - 384)] = v;
        }
    }
}

// ---------------- fused per-node edge phase, two-mode, shuffle-free ----------------
// Mode A: thread = (slot 0..31, head 0..3): serial f-dot in registers -> p in LDS.
// Mode B: thread = channel 0..127: weighted aggregation with p broadcast from LDS.
__global__ __launch_bounds__(128) void node_agg2(
    const unsigned short* __restrict__ elm,   // [N][128] bf16 (el_mut)
    const unsigned short* __restrict__ els,   // [N][128] bf16 (el_self)
    const float* __restrict__ er_mut,         // [N][128] f32
    const float* __restrict__ attn,           // [128]
    const int* __restrict__ offsets, const int* __restrict__ counts,
    const int* __restrict__ srcbuck, float* __restrict__ out)
{
    __shared__ float pl[32][4];
    __shared__ int   snb[32];

    const int n    = blockIdx.x;
    const int tid  = threadIdx.x;
    const int slot = tid >> 2;     // 0..31
    const int h    = tid & 3;      // 0..3 (mode A head)
    const int hB   = tid >> 5;     // 0..3 (mode B head)
    const int beg  = offsets[n];
    const int deg  = counts[n];

    // per-thread attn + er rows for head h (32 each) in registers
    float at[32], er[32];
    {
        const float4* ap = (const float4*)(attn + h * 32);
        const float4* ep = (const float4*)(er_mut + (size_t)n * HF + h * 32);
        #pragma unroll
        for (int q = 0; q < 8; ++q) {
            float4 a = ap[q], e = ep[q];
            at[q*4+0]=a.x; at[q*4+1]=a.y; at[q*4+2]=a.z; at[q*4+3]=a.w;
            er[q*4+0]=e.x; er[q*4+1]=e.y; er[q*4+2]=e.z; er[q*4+3]=e.w;
        }
    }

    float acc0 = 0.f, acc1 = 0.f, l0 = 0.f, l1 = 0.f;

    for (int done = 0; done < deg; done += 32) {
        const int cnt = min(32, deg - done);
        // ---- mode A ----
        if (slot < cnt) {
            int sn = srcbuck[beg + done + slot];
            if (h == 0) snb[slot] = sn;
            const uint4* rp = (const uint4*)(elm + (size_t)sn * HF + h * 32);
            uint4 q0 = rp[0], q1 = rp[1], q2 = rp[2], q3 = rp[3];
            unsigned uu[16] = {q0.x,q0.y,q0.z,q0.w, q1.x,q1.y,q1.z,q1.w,
                               q2.x,q2.y,q2.z,q2.w, q3.x,q3.y,q3.z,q3.w};
            float s = 0.f;
            #pragma unroll
            for (int q = 0; q < 16; ++q) {
                float z0 = bflo(uu[q]) + er[2*q];
                float z1 = bfhi(uu[q]) + er[2*q+1];
                z0 = (z0 > 0.f) ? z0 : NEG_SLOPE * z0;
                z1 = (z1 > 0.f) ? z1 : NEG_SLOPE * z1;
                s = fmaf(at[2*q],   z0, s);
                s = fmaf(at[2*q+1], z1, s);
            }
            pl[slot][h] = __expf(s);
        }
        __syncthreads();
        // ---- mode B ----
        int j = 0;
        for (; j + 3 < cnt; j += 4) {
            int s0 = snb[j], s1 = snb[j+1], s2 = snb[j+2], s3 = snb[j+3];
            float p0 = pl[j][hB], p1 = pl[j+1][hB], p2 = pl[j+2][hB], p3 = pl[j+3][hB];
            float c0 = bf1(els[(size_t)s0 * HF + tid]);
            float c1 = bf1(els[(size_t)s1 * HF + tid]);
            float c2 = bf1(els[(size_t)s2 * HF + tid]);
            float c3 = bf1(els[(size_t)s3 * HF + tid]);
            acc0 = fmaf(p0, c0, acc0); acc1 = fmaf(p1, c1, acc1);
            acc0 = fmaf(p2, c2, acc0); acc1 = fmaf(p3, c3, acc1);
            l0 += p0 + p2; l1 += p1 + p3;
        }
        for (; j < cnt; ++j) {
            int s0 = snb[j];
            float p0 = pl[j][hB];
            float c0 = bf1(els[(size_t)s0 * HF + tid]);
            acc0 = fmaf(p0, c0, acc0);
            l0 += p0;
        }
        __syncthreads();
    }

    float l = l0 + l1;
    float acc = acc0 + acc1;
    float r = (l > 0.f) ? (acc / l) : 0.f;
    out[(size_t)n * OUTC + FF + tid] = r;
}

extern "C" void kernel_launch(void* const* d_in, const int* in_sizes, int n_in,
                              void* d_out, int out_size, void* d_ws, size_t ws_size,
                              hipStream_t stream) {
    const float* feat   = (const float*)d_in[0];
    const float* W_src  = (const float*)d_in[1];
    const float* b_src  = (const float*)d_in[2];
    const float* W_dst  = (const float*)d_in[3];
    const float* b_dst  = (const float*)d_in[4];
    const float* W_self = (const float*)d_in[5];
    const float* b_self = (const float*)d_in[6];
    const float* W_lin  = (const float*)d_in[7];
    const float* b_lin  = (const float*)d_in[8];
    const float* attn   = (const float*)d_in[9];
    const int*   src    = (const int*)d_in[10];
    const int*   dst    = (const int*)d_in[11];
    float* out = (float*)d_out;

    // workspace carve-up
    unsigned short* elm = (unsigned short*)d_ws;           // N*HF bf16
    unsigned short* els = elm + (size_t)NN * HF;           // N*HF bf16
    float* er_mut  = (float*)(els + (size_t)NN * HF);      // N*HF fp32
    int*   counts  = (int*)(er_mut + (size_t)NN * HF);
    int*   offsets = counts  + NN;
    int*   rank    = offsets + NN;                         // E ints
    int*   srcbuck = rank    + EE;                         // E ints
    int*   bsum    = srcbuck + EE;                         // SCAN_B
    int*   bprefix = bsum    + SCAN_B;                     // SCAN_B
    unsigned short* WbT = (unsigned short*)(bprefix + SCAN_B); // 416*128 bf16
    float* biasc   = (float*)(WbT + 416 * 128);            // 416 fp32

    // CSR build (hierarchical scan, atomic-free scatter)
    zero_counts<<<(NN + 255) / 256, 256, 0, stream>>>(counts);
    hist_kernel<<<(EE + 255) / 256, 256, 0, stream>>>(dst, counts, rank);
    scan_bsum <<<SCAN_B, 256, 0, stream>>>(counts, bsum);
    scan_top  <<<1, 256, 0, stream>>>(bsum, bprefix);
    scan_final<<<SCAN_B, 256, 0, stream>>>(counts, bprefix, offsets);
    scatter_kernel<<<(EE + 255) / 256, 256, 0, stream>>>(src, dst, offsets, rank, srcbuck);

    // projections
    prep_weights<<<(416 * 128 + 255) / 256, 256, 0, stream>>>(
        W_src, b_src, W_dst, b_dst, W_self, b_self, W_lin, b_lin, WbT, biasc);
    {
        dim3 grid((NN + 63) / 64, 2);
        proj_gemm_mfma<<<grid, 256, 0, stream>>>(feat, WbT, biasc,
                                                 elm, els, er_mut, out);
    }

    // fused edge phase
    node_agg2<<<NN, 128, 0, stream>>>(elm, els, er_mut, attn,
                                      offsets, counts, srcbuck, out);
}

// Round 7
// 268.584 us; speedup vs baseline: 1.6188x; 1.6188x over previous
//
#include <hip/hip_runtime.h>
#include <hip/hip_bf16.h>

// Problem constants (from reference)
#define NN 50000
#define EE 800000
#define INF_ 128
#define HH 4
#define FF 32
#define HF 128          // H*F
#define OUTC 160        // (H+1)*F per node
#define NEG_SLOPE 0.2f

#define SCAN_B 196      // ceil(50000/256)

typedef __attribute__((ext_vector_type(8))) short short8;
typedef __attribute__((ext_vector_type(4))) float f32x4;

// fp32 -> bf16 bits, round-to-nearest-even
__device__ __forceinline__ unsigned short f2bf(float f) {
    union { float f; unsigned u; } in; in.f = f;
    unsigned u = in.u;
    u += 0x7fffu + ((u >> 16) & 1u);
    return (unsigned short)(u >> 16);
}
__device__ __forceinline__ float bflo(unsigned w) {   // low ushort as bf16 -> f32
    return __uint_as_float(w << 16);
}
__device__ __forceinline__ float bfhi(unsigned w) {   // high ushort as bf16 -> f32
    return __uint_as_float(w & 0xffff0000u);
}

// ---------------- CSR build ----------------
__global__ void zero_counts(int* __restrict__ counts) {
    int idx = blockIdx.x * blockDim.x + threadIdx.x;
    if (idx < NN) counts[idx] = 0;
}

// histogram; atomic return value = rank of edge within its dst bucket
__global__ void hist_kernel(const int* __restrict__ dst, int* __restrict__ counts,
                            int* __restrict__ rank) {
    int e = blockIdx.x * blockDim.x + threadIdx.x;
    if (e < EE) rank[e] = atomicAdd(&counts[dst[e]], 1);
}

// phase 1: per-block sum of 256 counts
__global__ __launch_bounds__(256) void scan_bsum(
    const int* __restrict__ counts, int* __restrict__ bsum)
{
    __shared__ int sh[256];
    int t = threadIdx.x;
    int idx = blockIdx.x * 256 + t;
    sh[t] = (idx < NN) ? counts[idx] : 0;
    __syncthreads();
    #pragma unroll
    for (int off = 128; off > 0; off >>= 1) {
        if (t < off) sh[t] += sh[t + off];
        __syncthreads();
    }
    if (t == 0) bsum[blockIdx.x] = sh[0];
}

// phase 2: single-block exclusive scan of SCAN_B partials
__global__ __launch_bounds__(256) void scan_top(
    const int* __restrict__ bsum, int* __restrict__ bprefix)
{
    __shared__ int sh[256];
    int t = threadIdx.x;
    int v = (t < SCAN_B) ? bsum[t] : 0;
    sh[t] = v;
    __syncthreads();
    #pragma unroll
    for (int off = 1; off < 256; off <<= 1) {
        int u = (t >= off) ? sh[t - off] : 0;
        __syncthreads();
        sh[t] += u;
        __syncthreads();
    }
    if (t < SCAN_B) bprefix[t] = sh[t] - v;   // exclusive
}

// phase 3: per-block exclusive scan + block prefix -> offsets
__global__ __launch_bounds__(256) void scan_final(
    const int* __restrict__ counts, const int* __restrict__ bprefix,
    int* __restrict__ offsets)
{
    __shared__ int sh[256];
    int t = threadIdx.x;
    int idx = blockIdx.x * 256 + t;
    int v = (idx < NN) ? counts[idx] : 0;
    sh[t] = v;
    __syncthreads();
    #pragma unroll
    for (int off = 1; off < 256; off <<= 1) {
        int u = (t >= off) ? sh[t - off] : 0;
        __syncthreads();
        sh[t] += u;
        __syncthreads();
    }
    if (idx < NN) offsets[idx] = sh[t] - v + bprefix[blockIdx.x];
}

// atomic-free scatter using precomputed ranks
__global__ void scatter_kernel(const int* __restrict__ src, const int* __restrict__ dst,
                               const int* __restrict__ offsets, const int* __restrict__ rank,
                               int* __restrict__ srcbuck)
{
    int e = blockIdx.x * blockDim.x + threadIdx.x;
    if (e < EE) srcbuck[offsets[dst[e]] + rank[e]] = src[e];
}

// ---------------- weight prep: concat + transpose + bf16 ----------------
__global__ __launch_bounds__(256) void prep_weights(
    const float* __restrict__ W0, const float* __restrict__ b0,
    const float* __restrict__ W1, const float* __restrict__ b1,
    const float* __restrict__ W2, const float* __restrict__ b2,
    const float* __restrict__ W3, const float* __restrict__ b3,
    unsigned short* __restrict__ WbT, float* __restrict__ biasc)
{
    int idx = blockIdx.x * 256 + threadIdx.x;   // 416*128 = 53248
    if (idx >= 416 * 128) return;
    int n = idx >> 7, k = idx & 127;
    float v;
    if (n < 128)      v = W0[k * 128 + n];
    else if (n < 256) v = W1[k * 128 + (n - 128)];
    else if (n < 384) v = W2[k * 128 + (n - 256)];
    else              v = W3[k * 32  + (n - 384)];
    WbT[n * 128 + k] = f2bf(v);
    if (idx < 416) {
        float bv;
        if (idx < 128)      bv = b0[idx];
        else if (idx < 256) bv = b1[idx - 128];
        else if (idx < 384) bv = b2[idx - 256];
        else                bv = b3[idx - 384];
        biasc[idx] = bv;
    }
}

// ---------------- bf16 MFMA projection GEMM ----------------
// epilogue: cols 0-127 -> pack lo (el_mut bf16), 128-255 -> er_mut fp32,
//           256-383 -> pack hi (el_self bf16), 384-415 -> out feat_lin
#define LSTRIDE 136
__global__ __launch_bounds__(256) void proj_gemm_mfma(
    const float* __restrict__ feat,
    const unsigned short* __restrict__ WbT,
    const float* __restrict__ biasc,
    unsigned short* __restrict__ packs,   // as ushort: [n][c][2] = {mut, self}
    float* __restrict__ er_mut, float* __restrict__ out)
{
    __shared__ unsigned short As[64  * LSTRIDE];
    __shared__ unsigned short Bs[208 * LSTRIDE];

    const int tid  = threadIdx.x;
    const int row0 = blockIdx.x * 64;
    const int nbase = blockIdx.y * 208;

    #pragma unroll
    for (int it = 0; it < 8; ++it) {
        int f  = tid + it * 256;
        int r  = f >> 5;
        int k4 = f & 31;
        int grow = row0 + r;
        float4 v = make_float4(0.f, 0.f, 0.f, 0.f);
        if (grow < NN) v = ((const float4*)feat)[(size_t)grow * 32 + k4];
        unsigned p0 = (unsigned)f2bf(v.x) | ((unsigned)f2bf(v.y) << 16);
        unsigned p1 = (unsigned)f2bf(v.z) | ((unsigned)f2bf(v.w) << 16);
        uint2 pk; pk.x = p0; pk.y = p1;
        *(uint2*)&As[r * LSTRIDE + k4 * 4] = pk;
    }
    #pragma unroll
    for (int it = 0; it < 26; ++it) {
        int c  = tid + it * 256;
        int n  = c >> 5;
        int kc = c & 31;
        uint2 v = *(const uint2*)&WbT[(size_t)(nbase + n) * 128 + kc * 4];
        *(uint2*)&Bs[n * LSTRIDE + kc * 4] = v;
    }
    __syncthreads();

    const int wv   = tid >> 6;
    const int lane = tid & 63;
    const int m16  = lane & 15;
    const int quad = lane >> 4;

    f32x4 acc[13];
    #pragma unroll
    for (int t = 0; t < 13; ++t) acc[t] = (f32x4){0.f, 0.f, 0.f, 0.f};

    short8 afr[4];
    const unsigned short* Abase = &As[(wv * 16 + m16) * LSTRIDE + quad * 8];
    #pragma unroll
    for (int ks = 0; ks < 4; ++ks)
        afr[ks] = *(const short8*)(Abase + ks * 32);

    #pragma unroll
    for (int t = 0; t < 13; ++t) {
        const unsigned short* Bbase = &Bs[(t * 16 + m16) * LSTRIDE + quad * 8];
        #pragma unroll
        for (int ks = 0; ks < 4; ++ks) {
            short8 bfr = *(const short8*)(Bbase + ks * 32);
            acc[t] = __builtin_amdgcn_mfma_f32_16x16x32_bf16(afr[ks], bfr, acc[t], 0, 0, 0);
        }
    }

    #pragma unroll
    for (int t = 0; t < 13; ++t) {
        int col = nbase + t * 16 + m16;
        float bb = biasc[col];
        #pragma unroll
        for (int r = 0; r < 4; ++r) {
            int grow = row0 + wv * 16 + quad * 4 + r;
            if (grow >= NN) continue;
            float v = acc[t][r] + bb;
            if (col < 128)      packs[((size_t)grow * HF + col) * 2]       = f2bf(v);
            else if (col < 256) er_mut[(size_t)grow * HF + (col - 128)] = v;
            else if (col < 384) packs[((size_t)grow * HF + (col - 256)) * 2 + 1] = f2bf(v);
            else                out[(size_t)grow * OUTC + (col - 384)] = v;
        }
    }
}

// ---------------- fused edge phase: one wave per node, 4 channels/thread ----------------
// lane li (0..31) owns channels 4li..4li+3 (uint4 = 16B gather of packed mut|self).
// Wave halves process even/odd edges concurrently; 3-level xor-shuffle reduces the
// 8-lane head group; halves combined once at the end via shfl_xor(32).
__device__ __forceinline__ void edge4(
    const uint4 w, const float4 erv, const float4 atv,
    float& l, float& a0, float& a1, float& a2, float& a3)
{
    float z0 = bflo(w.x) + erv.x;
    float z1 = bflo(w.y) + erv.y;
    float z2 = bflo(w.z) + erv.z;
    float z3 = bflo(w.w) + erv.w;
    z0 = (z0 > 0.f) ? z0 : NEG_SLOPE * z0;
    z1 = (z1 > 0.f) ? z1 : NEG_SLOPE * z1;
    z2 = (z2 > 0.f) ? z2 : NEG_SLOPE * z2;
    z3 = (z3 > 0.f) ? z3 : NEG_SLOPE * z3;
    float s = atv.x * z0;
    s = fmaf(atv.y, z1, s);
    s = fmaf(atv.z, z2, s);
    s = fmaf(atv.w, z3, s);
    // reduce across the 8-lane head group (xor 1,2,4 stay within aligned groups of 8)
    s += __shfl_xor(s, 1, 64);
    s += __shfl_xor(s, 2, 64);
    s += __shfl_xor(s, 4, 64);
    float p = __expf(s);
    l += p;
    a0 = fmaf(p, bfhi(w.x), a0);
    a1 = fmaf(p, bfhi(w.y), a1);
    a2 = fmaf(p, bfhi(w.z), a2);
    a3 = fmaf(p, bfhi(w.w), a3);
}

__global__ __launch_bounds__(256) void node_agg3(
    const unsigned* __restrict__ pack, const float* __restrict__ er_mut,
    const float* __restrict__ attn,
    const int* __restrict__ offsets, const int* __restrict__ counts,
    const int* __restrict__ srcbuck, float* __restrict__ out)
{
    const int n = blockIdx.x * 4 + (threadIdx.x >> 6);
    if (n >= NN) return;
    const int lane = threadIdx.x & 63;
    const int half = lane >> 5;          // edge parity
    const int li   = lane & 31;          // channel group: 4li..4li+3

    const float4 atv = *(const float4*)(attn + li * 4);
    const float4 erv = *(const float4*)(er_mut + (size_t)n * HF + li * 4);
    const int beg = offsets[n];
    const int deg = counts[n];

    float l = 0.f, a0 = 0.f, a1 = 0.f, a2 = 0.f, a3 = 0.f;

    int j = half;
    for (; j + 2 < deg; j += 4) {        // 2 edges per half in flight (4 per wave)
        int sn0 = srcbuck[beg + j];
        int sn1 = srcbuck[beg + j + 2];
        uint4 w0 = *(const uint4*)(pack + (size_t)sn0 * HF + li * 4);
        uint4 w1 = *(const uint4*)(pack + (size_t)sn1 * HF + li * 4);
        edge4(w0, erv, atv, l, a0, a1, a2, a3);
        edge4(w1, erv, atv, l, a0, a1, a2, a3);
    }
    for (; j < deg; j += 2) {
        int sn = srcbuck[beg + j];
        uint4 w = *(const uint4*)(pack + (size_t)sn * HF + li * 4);
        edge4(w, erv, atv, l, a0, a1, a2, a3);
    }

    // combine the two halves
    l  += __shfl_xor(l,  32, 64);
    a0 += __shfl_xor(a0, 32, 64);
    a1 += __shfl_xor(a1, 32, 64);
    a2 += __shfl_xor(a2, 32, 64);
    a3 += __shfl_xor(a3, 32, 64);

    if (half == 0) {
        float inv = (l > 0.f) ? __frcp_rn(l) : 0.f;
        float4 r = make_float4(a0 * inv, a1 * inv, a2 * inv, a3 * inv);
        *(float4*)(out + (size_t)n * OUTC + FF + li * 4) = r;
    }
}

extern "C" void kernel_launch(void* const* d_in, const int* in_sizes, int n_in,
                              void* d_out, int out_size, void* d_ws, size_t ws_size,
                              hipStream_t stream) {
    const float* feat   = (const float*)d_in[0];
    const float* W_src  = (const float*)d_in[1];
    const float* b_src  = (const float*)d_in[2];
    const float* W_dst  = (const float*)d_in[3];
    const float* b_dst  = (const float*)d_in[4];
    const float* W_self = (const float*)d_in[5];
    const float* b_self = (const float*)d_in[6];
    const float* W_lin  = (const float*)d_in[7];
    const float* b_lin  = (const float*)d_in[8];
    const float* attn   = (const float*)d_in[9];
    const int*   src    = (const int*)d_in[10];
    const int*   dst    = (const int*)d_in[11];
    float* out = (float*)d_out;

    // workspace carve-up
    unsigned* pack = (unsigned*)d_ws;                      // N*HF uints (bf16 mut|self)
    float* er_mut  = (float*)(pack + (size_t)NN * HF);     // N*HF fp32
    int*   counts  = (int*)(er_mut + (size_t)NN * HF);
    int*   offsets = counts  + NN;
    int*   rank    = offsets + NN;                         // E ints
    int*   srcbuck = rank    + EE;                         // E ints
    int*   bsum    = srcbuck + EE;                         // SCAN_B
    int*   bprefix = bsum    + SCAN_B;                     // SCAN_B
    unsigned short* WbT = (unsigned short*)(bprefix + SCAN_B); // 416*128 bf16
    float* biasc   = (float*)(WbT + 416 * 128);            // 416 fp32

    // CSR build (hierarchical scan, atomic-free scatter)
    zero_counts<<<(NN + 255) / 256, 256, 0, stream>>>(counts);
    hist_kernel<<<(EE + 255) / 256, 256, 0, stream>>>(dst, counts, rank);
    scan_bsum <<<SCAN_B, 256, 0, stream>>>(counts, bsum);
    scan_top  <<<1, 256, 0, stream>>>(bsum, bprefix);
    scan_final<<<SCAN_B, 256, 0, stream>>>(counts, bprefix, offsets);
    scatter_kernel<<<(EE + 255) / 256, 256, 0, stream>>>(src, dst, offsets, rank, srcbuck);

    // projections
    prep_weights<<<(416 * 128 + 255) / 256, 256, 0, stream>>>(
        W_src, b_src, W_dst, b_dst, W_self, b_self, W_lin, b_lin, WbT, biasc);
    {
        dim3 grid((NN + 63) / 64, 2);
        proj_gemm_mfma<<<grid, 256, 0, stream>>>(feat, WbT, biasc,
                                                 (unsigned short*)pack, er_mut, out);
    }

    // fused edge phase: one wave per node
    node_agg3<<<(NN + 3) / 4, 256, 0, stream>>>(pack, er_mut, attn,
                                                offsets, counts, srcbuck, out);
}

// Round 8
// 263.559 us; speedup vs baseline: 1.6497x; 1.0191x over previous
//
#include <hip/hip_runtime.h>
#include <hip/hip_bf16.h>

// Problem constants (from reference)
#define NN 50000
#define EE 800000
#define INF_ 128
#define HH 4
#define FF 32
#define HF 128          // H*F
#define OUTC 160        // (H+1)*F per node
#define NEG_SLOPE 0.2f

#define SCAN_B 196      // ceil(50000/256)
#define NROWS_PAD 50048 // 782*64 (GEMM reads padded A rows; OOB rows discarded)

typedef __attribute__((ext_vector_type(8))) short short8;
typedef __attribute__((ext_vector_type(4))) float f32x4;

// fp32 -> bf16 bits, round-to-nearest-even
__device__ __forceinline__ unsigned short f2bf(float f) {
    union { float f; unsigned u; } in; in.f = f;
    unsigned u = in.u;
    u += 0x7fffu + ((u >> 16) & 1u);
    return (unsigned short)(u >> 16);
}
__device__ __forceinline__ float bflo(unsigned w) {   // low ushort as bf16 -> f32
    return __uint_as_float(w << 16);
}
__device__ __forceinline__ float bfhi(unsigned w) {   // high ushort as bf16 -> f32
    return __uint_as_float(w & 0xffff0000u);
}

// async global->LDS 16B copy: LDS dest = wave-uniform base + lane*16
__device__ __forceinline__ void async_cp16(const void* g, void* l) {
    __builtin_amdgcn_global_load_lds(
        (const __attribute__((address_space(1))) void*)g,
        (__attribute__((address_space(3))) void*)l, 16, 0, 0);
}

// ---------------- CSR build ----------------
__global__ void zero_counts(int* __restrict__ counts) {
    int idx = blockIdx.x * blockDim.x + threadIdx.x;
    if (idx < NN) counts[idx] = 0;
}

// histogram; atomic return value = rank of edge within its dst bucket
__global__ void hist_kernel(const int* __restrict__ dst, int* __restrict__ counts,
                            int* __restrict__ rank) {
    int e = blockIdx.x * blockDim.x + threadIdx.x;
    if (e < EE) rank[e] = atomicAdd(&counts[dst[e]], 1);
}

__global__ __launch_bounds__(256) void scan_bsum(
    const int* __restrict__ counts, int* __restrict__ bsum)
{
    __shared__ int sh[256];
    int t = threadIdx.x;
    int idx = blockIdx.x * 256 + t;
    sh[t] = (idx < NN) ? counts[idx] : 0;
    __syncthreads();
    #pragma unroll
    for (int off = 128; off > 0; off >>= 1) {
        if (t < off) sh[t] += sh[t + off];
        __syncthreads();
    }
    if (t == 0) bsum[blockIdx.x] = sh[0];
}

__global__ __launch_bounds__(256) void scan_top(
    const int* __restrict__ bsum, int* __restrict__ bprefix)
{
    __shared__ int sh[256];
    int t = threadIdx.x;
    int v = (t < SCAN_B) ? bsum[t] : 0;
    sh[t] = v;
    __syncthreads();
    #pragma unroll
    for (int off = 1; off < 256; off <<= 1) {
        int u = (t >= off) ? sh[t - off] : 0;
        __syncthreads();
        sh[t] += u;
        __syncthreads();
    }
    if (t < SCAN_B) bprefix[t] = sh[t] - v;   // exclusive
}

__global__ __launch_bounds__(256) void scan_final(
    const int* __restrict__ counts, const int* __restrict__ bprefix,
    int* __restrict__ offsets)
{
    __shared__ int sh[256];
    int t = threadIdx.x;
    int idx = blockIdx.x * 256 + t;
    int v = (idx < NN) ? counts[idx] : 0;
    sh[t] = v;
    __syncthreads();
    #pragma unroll
    for (int off = 1; off < 256; off <<= 1) {
        int u = (t >= off) ? sh[t - off] : 0;
        __syncthreads();
        sh[t] += u;
        __syncthreads();
    }
    if (idx < NN) offsets[idx] = sh[t] - v + bprefix[blockIdx.x];
}

__global__ void scatter_kernel(const int* __restrict__ src, const int* __restrict__ dst,
                               const int* __restrict__ offsets, const int* __restrict__ rank,
                               int* __restrict__ srcbuck)
{
    int e = blockIdx.x * blockDim.x + threadIdx.x;
    if (e < EE) srcbuck[offsets[dst[e]] + rank[e]] = src[e];
}

// ---------------- feat -> bf16, XOR-swizzled 16B chunks ----------------
// chunk c (8 bf16) of row r stored at physical chunk c ^ (r & 15)
__global__ __launch_bounds__(256) void prep_feat(
    const float* __restrict__ feat, unsigned short* __restrict__ fb)
{
    int idx = blockIdx.x * 256 + threadIdx.x;   // NN*16 = 800000 chunks
    if (idx >= NN * 16) return;
    int r = idx >> 4, c = idx & 15;
    const float4* fp = (const float4*)(feat + (size_t)r * 128 + c * 8);
    float4 v0 = fp[0], v1 = fp[1];
    uint4 o;
    o.x = (unsigned)f2bf(v0.x) | ((unsigned)f2bf(v0.y) << 16);
    o.y = (unsigned)f2bf(v0.z) | ((unsigned)f2bf(v0.w) << 16);
    o.z = (unsigned)f2bf(v1.x) | ((unsigned)f2bf(v1.y) << 16);
    o.w = (unsigned)f2bf(v1.z) | ((unsigned)f2bf(v1.w) << 16);
    *(uint4*)(fb + (size_t)r * 128 + ((c ^ (r & 15)) << 3)) = o;
}

// ---------------- weight prep: concat + transpose + bf16, same swizzle ----------------
__global__ __launch_bounds__(256) void prep_weights(
    const float* __restrict__ W0, const float* __restrict__ b0,
    const float* __restrict__ W1, const float* __restrict__ b1,
    const float* __restrict__ W2, const float* __restrict__ b2,
    const float* __restrict__ W3, const float* __restrict__ b3,
    unsigned short* __restrict__ WbT, float* __restrict__ biasc)
{
    int idx = blockIdx.x * 256 + threadIdx.x;   // 416*128 = 53248
    if (idx >= 416 * 128) return;
    int n = idx >> 7, k = idx & 127;
    float v;
    if (n < 128)      v = W0[k * 128 + n];
    else if (n < 256) v = W1[k * 128 + (n - 128)];
    else if (n < 384) v = W2[k * 128 + (n - 256)];
    else              v = W3[k * 32  + (n - 384)];
    int phys = (((k >> 3) ^ (n & 15)) << 3) | (k & 7);
    WbT[n * 128 + phys] = f2bf(v);
    if (idx < 416) {
        float bv;
        if (idx < 128)      bv = b0[idx];
        else if (idx < 256) bv = b1[idx - 128];
        else if (idx < 384) bv = b2[idx - 256];
        else                bv = b3[idx - 384];
        biasc[idx] = bv;
    }
}

// ---------------- bf16 MFMA projection GEMM, async-staged ----------------
// 64 rows x 208 cols per block, 4 waves. A/B staged via global_load_lds (16B),
// linear rows of 256B; XOR chunk swizzle makes b128 frag reads 2-way (free).
__global__ __launch_bounds__(256) void proj_gemm_mfma(
    const unsigned short* __restrict__ featb,
    const unsigned short* __restrict__ WbT,
    const float* __restrict__ biasc,
    unsigned short* __restrict__ packs,   // as ushort: [n][c][2] = {mut, self}
    float* __restrict__ er_mut, float* __restrict__ out)
{
    __shared__ __align__(16) unsigned short As[64 * 128];    // 16 KB
    __shared__ __align__(16) unsigned short Bs[208 * 128];   // 53.25 KB

    const int tid  = threadIdx.x;
    const int wv   = tid >> 6;
    const int lane = tid & 63;
    const int row0 = blockIdx.x * 64;
    const int nbase = blockIdx.y * 208;

    // async stage A: 16 KB = 16 segs of 1024B; wave wv -> segs [4wv, 4wv+4)
    {
        const char* g = (const char*)(featb + (size_t)row0 * 128);
        char* l = (char*)As;
        #pragma unroll
        for (int it = 0; it < 4; ++it) {
            int seg = wv * 4 + it;
            async_cp16(g + seg * 1024 + lane * 16, l + seg * 1024);
        }
    }
    // async stage B: 53248 B = 52 segs; wave wv -> segs [13wv, 13wv+13)
    {
        const char* g = (const char*)(WbT + (size_t)nbase * 128);
        char* l = (char*)Bs;
        #pragma unroll
        for (int it = 0; it < 13; ++it) {
            int seg = wv * 13 + it;
            async_cp16(g + seg * 1024 + lane * 16, l + seg * 1024);
        }
    }
    __syncthreads();   // drains vmcnt incl. global_load_lds

    const int m16  = lane & 15;
    const int quad = lane >> 4;

    f32x4 acc[13];
    #pragma unroll
    for (int t = 0; t < 13; ++t) acc[t] = (f32x4){0.f, 0.f, 0.f, 0.f};

    // A frags: logical chunk = ks*4+quad, phys = chunk ^ m16
    short8 afr[4];
    {
        const unsigned short* Ab = As + (wv * 16 + m16) * 128;
        #pragma unroll
        for (int ks = 0; ks < 4; ++ks)
            afr[ks] = *(const short8*)(Ab + (((ks * 4 + quad) ^ m16) << 3));
    }

    #pragma unroll
    for (int t = 0; t < 13; ++t) {
        const unsigned short* Bb = Bs + (t * 16 + m16) * 128;
        #pragma unroll
        for (int ks = 0; ks < 4; ++ks) {
            short8 bfr = *(const short8*)(Bb + (((ks * 4 + quad) ^ m16) << 3));
            acc[t] = __builtin_amdgcn_mfma_f32_16x16x32_bf16(afr[ks], bfr, acc[t], 0, 0, 0);
        }
    }

    // epilogue: C/D layout col=lane&15, row=quad*4+reg
    #pragma unroll
    for (int t = 0; t < 13; ++t) {
        int col = nbase + t * 16 + m16;
        float bb = biasc[col];
        #pragma unroll
        for (int r = 0; r < 4; ++r) {
            int grow = row0 + wv * 16 + quad * 4 + r;
            if (grow >= NN) continue;
            float v = acc[t][r] + bb;
            if (col < 128)      packs[((size_t)grow * HF + col) * 2]       = f2bf(v);
            else if (col < 256) er_mut[(size_t)grow * HF + (col - 128)] = v;
            else if (col < 384) packs[((size_t)grow * HF + (col - 256)) * 2 + 1] = f2bf(v);
            else                out[(size_t)grow * OUTC + (col - 384)] = v;
        }
    }
}

// ---------------- fused edge phase: one wave per node, 4 channels/thread ----------------
__device__ __forceinline__ void edge4(
    const uint4 w, const float4 erv, const float4 atv,
    float& l, float& a0, float& a1, float& a2, float& a3)
{
    float z0 = bflo(w.x) + erv.x;
    float z1 = bflo(w.y) + erv.y;
    float z2 = bflo(w.z) + erv.z;
    float z3 = bflo(w.w) + erv.w;
    z0 = (z0 > 0.f) ? z0 : NEG_SLOPE * z0;
    z1 = (z1 > 0.f) ? z1 : NEG_SLOPE * z1;
    z2 = (z2 > 0.f) ? z2 : NEG_SLOPE * z2;
    z3 = (z3 > 0.f) ? z3 : NEG_SLOPE * z3;
    float s = atv.x * z0;
    s = fmaf(atv.y, z1, s);
    s = fmaf(atv.z, z2, s);
    s = fmaf(atv.w, z3, s);
    s += __shfl_xor(s, 1, 64);
    s += __shfl_xor(s, 2, 64);
    s += __shfl_xor(s, 4, 64);
    float p = __expf(s);
    l += p;
    a0 = fmaf(p, bfhi(w.x), a0);
    a1 = fmaf(p, bfhi(w.y), a1);
    a2 = fmaf(p, bfhi(w.z), a2);
    a3 = fmaf(p, bfhi(w.w), a3);
}

__global__ __launch_bounds__(256) void node_agg3(
    const unsigned* __restrict__ pack, const float* __restrict__ er_mut,
    const float* __restrict__ attn,
    const int* __restrict__ offsets, const int* __restrict__ counts,
    const int* __restrict__ srcbuck, float* __restrict__ out)
{
    const int n = blockIdx.x * 4 + (threadIdx.x >> 6);
    if (n >= NN) return;
    const int lane = threadIdx.x & 63;
    const int half = lane >> 5;          // edge parity
    const int li   = lane & 31;          // channel group: 4li..4li+3

    const float4 atv = *(const float4*)(attn + li * 4);
    const float4 erv = *(const float4*)(er_mut + (size_t)n * HF + li * 4);
    const int beg = offsets[n];
    const int deg = counts[n];

    float l = 0.f, a0 = 0.f, a1 = 0.f, a2 = 0.f, a3 = 0.f;

    int j = half;
    for (; j + 2 < deg; j += 4) {
        int sn0 = srcbuck[beg + j];
        int sn1 = srcbuck[beg + j + 2];
        uint4 w0 = *(const uint4*)(pack + (size_t)sn0 * HF + li * 4);
        uint4 w1 = *(const uint4*)(pack + (size_t)sn1 * HF + li * 4);
        edge4(w0, erv, atv, l, a0, a1, a2, a3);
        edge4(w1, erv, atv, l, a0, a1, a2, a3);
    }
    for (; j < deg; j += 2) {
        int sn = srcbuck[beg + j];
        uint4 w = *(const uint4*)(pack + (size_t)sn * HF + li * 4);
        edge4(w, erv, atv, l, a0, a1, a2, a3);
    }

    l  += __shfl_xor(l,  32, 64);
    a0 += __shfl_xor(a0, 32, 64);
    a1 += __shfl_xor(a1, 32, 64);
    a2 += __shfl_xor(a2, 32, 64);
    a3 += __shfl_xor(a3, 32, 64);

    if (half == 0) {
        float inv = (l > 0.f) ? __frcp_rn(l) : 0.f;
        float4 r = make_float4(a0 * inv, a1 * inv, a2 * inv, a3 * inv);
        *(float4*)(out + (size_t)n * OUTC + FF + li * 4) = r;
    }
}

extern "C" void kernel_launch(void* const* d_in, const int* in_sizes, int n_in,
                              void* d_out, int out_size, void* d_ws, size_t ws_size,
                              hipStream_t stream) {
    const float* feat   = (const float*)d_in[0];
    const float* W_src  = (const float*)d_in[1];
    const float* b_src  = (const float*)d_in[2];
    const float* W_dst  = (const float*)d_in[3];
    const float* b_dst  = (const float*)d_in[4];
    const float* W_self = (const float*)d_in[5];
    const float* b_self = (const float*)d_in[6];
    const float* W_lin  = (const float*)d_in[7];
    const float* b_lin  = (const float*)d_in[8];
    const float* attn   = (const float*)d_in[9];
    const int*   src    = (const int*)d_in[10];
    const int*   dst    = (const int*)d_in[11];
    float* out = (float*)d_out;

    // workspace carve-up
    unsigned* pack = (unsigned*)d_ws;                      // N*HF uints (bf16 mut|self)
    float* er_mut  = (float*)(pack + (size_t)NN * HF);     // N*HF fp32
    unsigned short* featb = (unsigned short*)(er_mut + (size_t)NN * HF); // NROWS_PAD*128 bf16
    unsigned short* WbT   = featb + (size_t)NROWS_PAD * 128;             // 416*128 bf16
    float* biasc   = (float*)(WbT + 416 * 128);            // 416 fp32
    int*   counts  = (int*)(biasc + 416);
    int*   offsets = counts  + NN;
    int*   rank    = offsets + NN;                         // E ints
    int*   srcbuck = rank    + EE;                         // E ints
    int*   bsum    = srcbuck + EE;                         // SCAN_B
    int*   bprefix = bsum    + SCAN_B;                     // SCAN_B

    // CSR build (hierarchical scan, atomic-free scatter)
    zero_counts<<<(NN + 255) / 256, 256, 0, stream>>>(counts);
    hist_kernel<<<(EE + 255) / 256, 256, 0, stream>>>(dst, counts, rank);
    scan_bsum <<<SCAN_B, 256, 0, stream>>>(counts, bsum);
    scan_top  <<<1, 256, 0, stream>>>(bsum, bprefix);
    scan_final<<<SCAN_B, 256, 0, stream>>>(counts, bprefix, offsets);
    scatter_kernel<<<(EE + 255) / 256, 256, 0, stream>>>(src, dst, offsets, rank, srcbuck);

    // projections
    prep_feat<<<(NN * 16 + 255) / 256, 256, 0, stream>>>(feat, featb);
    prep_weights<<<(416 * 128 + 255) / 256, 256, 0, stream>>>(
        W_src, b_src, W_dst, b_dst, W_self, b_self, W_lin, b_lin, WbT, biasc);
    {
        dim3 grid((NN + 63) / 64, 2);
        proj_gemm_mfma<<<grid, 256, 0, stream>>>(featb, WbT, biasc,
                                                 (unsigned short*)pack, er_mut, out);
    }

    // fused edge phase: one wave per node
    node_agg3<<<(NN + 3) / 4, 256, 0, stream>>>(pack, er_mut, attn,
                                                offsets, counts, srcbuck, out);
}

// Round 9
// 261.980 us; speedup vs baseline: 1.6596x; 1.0060x over previous
//
#include <hip/hip_runtime.h>
#include <hip/hip_bf16.h>

// Problem constants (from reference)
#define NN 50000
#define EE 800000
#define INF_ 128
#define HH 4
#define FF 32
#define HF 128          // H*F
#define OUTC 160        // (H+1)*F per node
#define NEG_SLOPE 0.2f

#define SCAN_B 196      // ceil(50000/256)
#define NROWS_PAD 50048 // 782*64 (GEMM reads padded A rows; OOB rows discarded)

typedef __attribute__((ext_vector_type(8))) short short8;
typedef __attribute__((ext_vector_type(4))) float f32x4;
typedef _Float16 f16x2 __attribute__((ext_vector_type(2)));
typedef float fl2 __attribute__((ext_vector_type(2)));

// fp32 -> bf16 bits, round-to-nearest-even
__device__ __forceinline__ unsigned short f2bf(float f) {
    union { float f; unsigned u; } in; in.f = f;
    unsigned u = in.u;
    u += 0x7fffu + ((u >> 16) & 1u);
    return (unsigned short)(u >> 16);
}
__device__ __forceinline__ unsigned short f2h(float f) {
    _Float16 h = (_Float16)f;
    return __builtin_bit_cast(unsigned short, h);
}
__device__ __forceinline__ f16x2 bch(unsigned u) {
    return __builtin_bit_cast(f16x2, u);
}
__device__ __forceinline__ f16x2 habs2(f16x2 v) {
    unsigned u = __builtin_bit_cast(unsigned, v) & 0x7FFF7FFFu;
    return __builtin_bit_cast(f16x2, u);
}

// async global->LDS 16B copy: LDS dest = wave-uniform base + lane*16
__device__ __forceinline__ void async_cp16(const void* g, void* l) {
    __builtin_amdgcn_global_load_lds(
        (const __attribute__((address_space(1))) void*)g,
        (__attribute__((address_space(3))) void*)l, 16, 0, 0);
}

// ---------------- CSR build ----------------
// histogram; atomic return value = rank of edge within its dst bucket
__global__ void hist_kernel(const int* __restrict__ dst, int* __restrict__ counts,
                            int* __restrict__ rank) {
    int e = blockIdx.x * blockDim.x + threadIdx.x;
    if (e < EE) rank[e] = atomicAdd(&counts[dst[e]], 1);
}

__global__ __launch_bounds__(256) void scan_bsum(
    const int* __restrict__ counts, int* __restrict__ bsum)
{
    __shared__ int sh[256];
    int t = threadIdx.x;
    int idx = blockIdx.x * 256 + t;
    sh[t] = (idx < NN) ? counts[idx] : 0;
    __syncthreads();
    #pragma unroll
    for (int off = 128; off > 0; off >>= 1) {
        if (t < off) sh[t] += sh[t + off];
        __syncthreads();
    }
    if (t == 0) bsum[blockIdx.x] = sh[0];
}

__global__ __launch_bounds__(256) void scan_top(
    const int* __restrict__ bsum, int* __restrict__ bprefix)
{
    __shared__ int sh[256];
    int t = threadIdx.x;
    int v = (t < SCAN_B) ? bsum[t] : 0;
    sh[t] = v;
    __syncthreads();
    #pragma unroll
    for (int off = 1; off < 256; off <<= 1) {
        int u = (t >= off) ? sh[t - off] : 0;
        __syncthreads();
        sh[t] += u;
        __syncthreads();
    }
    if (t < SCAN_B) bprefix[t] = sh[t] - v;   // exclusive
}

__global__ __launch_bounds__(256) void scan_final(
    const int* __restrict__ counts, const int* __restrict__ bprefix,
    int* __restrict__ offsets)
{
    __shared__ int sh[256];
    int t = threadIdx.x;
    int idx = blockIdx.x * 256 + t;
    int v = (idx < NN) ? counts[idx] : 0;
    sh[t] = v;
    __syncthreads();
    #pragma unroll
    for (int off = 1; off < 256; off <<= 1) {
        int u = (t >= off) ? sh[t - off] : 0;
        __syncthreads();
        sh[t] += u;
        __syncthreads();
    }
    if (idx < NN) offsets[idx] = sh[t] - v + bprefix[blockIdx.x];
}

__global__ void scatter_kernel(const int* __restrict__ src, const int* __restrict__ dst,
                               const int* __restrict__ offsets, const int* __restrict__ rank,
                               int* __restrict__ srcbuck)
{
    int e = blockIdx.x * blockDim.x + threadIdx.x;
    if (e < EE) srcbuck[offsets[dst[e]] + rank[e]] = src[e];
}

// ---------------- feat -> bf16, XOR-swizzled 16B chunks ----------------
__global__ __launch_bounds__(256) void prep_feat(
    const float* __restrict__ feat, unsigned short* __restrict__ fb)
{
    int idx = blockIdx.x * 256 + threadIdx.x;   // NN*16 = 800000 chunks
    if (idx >= NN * 16) return;
    int r = idx >> 4, c = idx & 15;
    const float4* fp = (const float4*)(feat + (size_t)r * 128 + c * 8);
    float4 v0 = fp[0], v1 = fp[1];
    uint4 o;
    o.x = (unsigned)f2bf(v0.x) | ((unsigned)f2bf(v0.y) << 16);
    o.y = (unsigned)f2bf(v0.z) | ((unsigned)f2bf(v0.w) << 16);
    o.z = (unsigned)f2bf(v1.x) | ((unsigned)f2bf(v1.y) << 16);
    o.w = (unsigned)f2bf(v1.z) | ((unsigned)f2bf(v1.w) << 16);
    *(uint4*)(fb + (size_t)r * 128 + ((c ^ (r & 15)) << 3)) = o;
}

// ---------------- weight prep: concat + transpose + bf16, same swizzle ----------------
__global__ __launch_bounds__(256) void prep_weights(
    const float* __restrict__ W0, const float* __restrict__ b0,
    const float* __restrict__ W1, const float* __restrict__ b1,
    const float* __restrict__ W2, const float* __restrict__ b2,
    const float* __restrict__ W3, const float* __restrict__ b3,
    const float* __restrict__ attn,
    unsigned short* __restrict__ WbT, float* __restrict__ biasc,
    unsigned short* __restrict__ ath)
{
    int idx = blockIdx.x * 256 + threadIdx.x;   // 416*128 = 53248
    if (idx >= 416 * 128) return;
    int n = idx >> 7, k = idx & 127;
    float v;
    if (n < 128)      v = W0[k * 128 + n];
    else if (n < 256) v = W1[k * 128 + (n - 128)];
    else if (n < 384) v = W2[k * 128 + (n - 256)];
    else              v = W3[k * 32  + (n - 384)];
    int phys = (((k >> 3) ^ (n & 15)) << 3) | (k & 7);
    WbT[n * 128 + phys] = f2bf(v);
    if (idx < 416) {
        float bv;
        if (idx < 128)      bv = b0[idx];
        else if (idx < 256) bv = b1[idx - 128];
        else if (idx < 384) bv = b2[idx - 256];
        else                bv = b3[idx - 384];
        biasc[idx] = bv;
    }
    if (idx < 128) ath[idx] = f2h(attn[idx]);   // channel-order packed f16
}

// ---------------- bf16 MFMA projection GEMM, async-staged ----------------
// epilogue layouts:
//  pack (f16, 256 ushort/node): channel c -> group g=c>>2 (8 ushorts):
//    mut  at g*8 + ((r>>1)<<2) + (r&1),  self at +2   (r = c&3)
//    => lane li uint4 = {mut01, self01, mut23, self23} for channels 4li..4li+3
//  erh  (f16, 128 ushort/node): linear channel order
__global__ __launch_bounds__(256) void proj_gemm_mfma(
    const unsigned short* __restrict__ featb,
    const unsigned short* __restrict__ WbT,
    const float* __restrict__ biasc,
    unsigned short* __restrict__ packs,
    unsigned short* __restrict__ erh, float* __restrict__ out)
{
    __shared__ __align__(16) unsigned short As[64 * 128];    // 16 KB
    __shared__ __align__(16) unsigned short Bs[208 * 128];   // 53.25 KB

    const int tid  = threadIdx.x;
    const int wv   = tid >> 6;
    const int lane = tid & 63;
    const int row0 = blockIdx.x * 64;
    const int nbase = blockIdx.y * 208;

    {
        const char* g = (const char*)(featb + (size_t)row0 * 128);
        char* l = (char*)As;
        #pragma unroll
        for (int it = 0; it < 4; ++it) {
            int seg = wv * 4 + it;
            async_cp16(g + seg * 1024 + lane * 16, l + seg * 1024);
        }
    }
    {
        const char* g = (const char*)(WbT + (size_t)nbase * 128);
        char* l = (char*)Bs;
        #pragma unroll
        for (int it = 0; it < 13; ++it) {
            int seg = wv * 13 + it;
            async_cp16(g + seg * 1024 + lane * 16, l + seg * 1024);
        }
    }
    __syncthreads();

    const int m16  = lane & 15;
    const int quad = lane >> 4;

    f32x4 acc[13];
    #pragma unroll
    for (int t = 0; t < 13; ++t) acc[t] = (f32x4){0.f, 0.f, 0.f, 0.f};

    short8 afr[4];
    {
        const unsigned short* Ab = As + (wv * 16 + m16) * 128;
        #pragma unroll
        for (int ks = 0; ks < 4; ++ks)
            afr[ks] = *(const short8*)(Ab + (((ks * 4 + quad) ^ m16) << 3));
    }

    #pragma unroll
    for (int t = 0; t < 13; ++t) {
        const unsigned short* Bb = Bs + (t * 16 + m16) * 128;
        #pragma unroll
        for (int ks = 0; ks < 4; ++ks) {
            short8 bfr = *(const short8*)(Bb + (((ks * 4 + quad) ^ m16) << 3));
            acc[t] = __builtin_amdgcn_mfma_f32_16x16x32_bf16(afr[ks], bfr, acc[t], 0, 0, 0);
        }
    }

    #pragma unroll
    for (int t = 0; t < 13; ++t) {
        int col = nbase + t * 16 + m16;
        float bb = biasc[col];
        #pragma unroll
        for (int r = 0; r < 4; ++r) {
            int grow = row0 + wv * 16 + quad * 4 + r;
            if (grow >= NN) continue;
            float v = acc[t][r] + bb;
            if (col < 128) {
                int c = col, rr = c & 3;
                packs[(size_t)grow * 256 + (c >> 2) * 8 + ((rr >> 1) << 2) + (rr & 1)] = f2h(v);
            } else if (col < 256) {
                erh[(size_t)grow * HF + (col - 128)] = f2h(v);
            } else if (col < 384) {
                int c = col - 256, rr = c & 3;
                packs[(size_t)grow * 256 + (c >> 2) * 8 + ((rr >> 1) << 2) + 2 + (rr & 1)] = f2h(v);
            } else {
                out[(size_t)grow * OUTC + (col - 384)] = v;
            }
        }
    }
}

// ---------------- fused edge phase: one wave/node, f16 dot2, 4-deep unroll ----------------
// leaky(z) = 0.6z + 0.4|z|  =>  s = 0.6*dot(at,z) + 0.4*dot(at,|z|)
__device__ __forceinline__ void edgeP(
    const uint4 w, const f16x2 er01, const f16x2 er23,
    const f16x2 at01, const f16x2 at23,
    float& l, float& a0, float& a1, float& a2, float& a3)
{
    f16x2 z01 = bch(w.x) + er01;
    f16x2 z23 = bch(w.z) + er23;
    float s1 = __builtin_amdgcn_fdot2(at01, z01, 0.f, false);
    s1 = __builtin_amdgcn_fdot2(at23, z23, s1, false);
    float s2 = __builtin_amdgcn_fdot2(at01, habs2(z01), 0.f, false);
    s2 = __builtin_amdgcn_fdot2(at23, habs2(z23), s2, false);
    float s = fmaf(0.6f, s1, 0.4f * s2);
    s += __shfl_xor(s, 1, 64);
    s += __shfl_xor(s, 2, 64);
    s += __shfl_xor(s, 4, 64);
    float p = __expf(s);
    l += p;
    fl2 c01 = __builtin_convertvector(bch(w.y), fl2);
    fl2 c23 = __builtin_convertvector(bch(w.w), fl2);
    a0 = fmaf(p, c01.x, a0);
    a1 = fmaf(p, c01.y, a1);
    a2 = fmaf(p, c23.x, a2);
    a3 = fmaf(p, c23.y, a3);
}

__global__ __launch_bounds__(256) void node_agg4(
    const uint4* __restrict__ pack,           // [N][32] uint4 (lane-local f16)
    const unsigned short* __restrict__ erh,   // [N][128] f16
    const unsigned short* __restrict__ ath,   // [128] f16
    const int* __restrict__ offsets, const int* __restrict__ counts,
    const int* __restrict__ srcbuck, float* __restrict__ out)
{
    const int n = blockIdx.x * 4 + (threadIdx.x >> 6);
    if (n >= NN) return;
    const int lane = threadIdx.x & 63;
    const int half = lane >> 5;          // contiguous half of the bucket
    const int li   = lane & 31;          // channel group: 4li..4li+3

    uint2 aw = *(const uint2*)(ath + li * 4);
    uint2 ew = *(const uint2*)(erh + (size_t)n * HF + li * 4);
    const f16x2 at01 = bch(aw.x), at23 = bch(aw.y);
    const f16x2 er01 = bch(ew.x), er23 = bch(ew.y);

    const int beg = offsets[n];
    const int deg = counts[n];
    const int cnt0 = (deg + 1) >> 1;
    const int st  = beg + (half ? cnt0 : 0);
    const int cnt = half ? (deg - cnt0) : cnt0;

    float l = 0.f, a0 = 0.f, a1 = 0.f, a2 = 0.f, a3 = 0.f;

    int k = 0;
    for (; k + 4 <= cnt; k += 4) {
        int i0 = srcbuck[st + k];
        int i1 = srcbuck[st + k + 1];
        int i2 = srcbuck[st + k + 2];
        int i3 = srcbuck[st + k + 3];
        uint4 w0 = pack[(size_t)i0 * 32 + li];
        uint4 w1 = pack[(size_t)i1 * 32 + li];
        uint4 w2 = pack[(size_t)i2 * 32 + li];
        uint4 w3 = pack[(size_t)i3 * 32 + li];
        edgeP(w0, er01, er23, at01, at23, l, a0, a1, a2, a3);
        edgeP(w1, er01, er23, at01, at23, l, a0, a1, a2, a3);
        edgeP(w2, er01, er23, at01, at23, l, a0, a1, a2, a3);
        edgeP(w3, er01, er23, at01, at23, l, a0, a1, a2, a3);
    }
    for (; k < cnt; ++k) {
        int i0 = srcbuck[st + k];
        uint4 w = pack[(size_t)i0 * 32 + li];
        edgeP(w, er01, er23, at01, at23, l, a0, a1, a2, a3);
    }

    l  += __shfl_xor(l,  32, 64);
    a0 += __shfl_xor(a0, 32, 64);
    a1 += __shfl_xor(a1, 32, 64);
    a2 += __shfl_xor(a2, 32, 64);
    a3 += __shfl_xor(a3, 32, 64);

    if (half == 0) {
        float inv = (l > 0.f) ? __frcp_rn(l) : 0.f;
        float4 r = make_float4(a0 * inv, a1 * inv, a2 * inv, a3 * inv);
        *(float4*)(out + (size_t)n * OUTC + FF + li * 4) = r;
    }
}

extern "C" void kernel_launch(void* const* d_in, const int* in_sizes, int n_in,
                              void* d_out, int out_size, void* d_ws, size_t ws_size,
                              hipStream_t stream) {
    const float* feat   = (const float*)d_in[0];
    const float* W_src  = (const float*)d_in[1];
    const float* b_src  = (const float*)d_in[2];
    const float* W_dst  = (const float*)d_in[3];
    const float* b_dst  = (const float*)d_in[4];
    const float* W_self = (const float*)d_in[5];
    const float* b_self = (const float*)d_in[6];
    const float* W_lin  = (const float*)d_in[7];
    const float* b_lin  = (const float*)d_in[8];
    const float* attn   = (const float*)d_in[9];
    const int*   src    = (const int*)d_in[10];
    const int*   dst    = (const int*)d_in[11];
    float* out = (float*)d_out;

    // workspace carve-up
    unsigned short* packs = (unsigned short*)d_ws;                  // N*256 f16
    unsigned short* erh   = packs + (size_t)NN * 256;               // N*128 f16
    unsigned short* featb = erh + (size_t)NN * HF;                  // NROWS_PAD*128 bf16
    unsigned short* WbT   = featb + (size_t)NROWS_PAD * 128;        // 416*128 bf16
    unsigned short* ath   = WbT + 416 * 128;                        // 128 f16
    float* biasc   = (float*)(ath + 128);                           // 416 fp32
    int*   counts  = (int*)(biasc + 416);
    int*   offsets = counts  + NN;
    int*   rank    = offsets + NN;                                  // E ints
    int*   srcbuck = rank    + EE;                                  // E ints
    int*   bsum    = srcbuck + EE;                                  // SCAN_B
    int*   bprefix = bsum    + SCAN_B;                              // SCAN_B

    // CSR build (hierarchical scan, atomic-free scatter)
    hipMemsetAsync(counts, 0, (size_t)NN * sizeof(int), stream);
    hist_kernel<<<(EE + 255) / 256, 256, 0, stream>>>(dst, counts, rank);
    scan_bsum <<<SCAN_B, 256, 0, stream>>>(counts, bsum);
    scan_top  <<<1, 256, 0, stream>>>(bsum, bprefix);
    scan_final<<<SCAN_B, 256, 0, stream>>>(counts, bprefix, offsets);
    scatter_kernel<<<(EE + 255) / 256, 256, 0, stream>>>(src, dst, offsets, rank, srcbuck);

    // projections
    prep_feat<<<(NN * 16 + 255) / 256, 256, 0, stream>>>(feat, featb);
    prep_weights<<<(416 * 128 + 255) / 256, 256, 0, stream>>>(
        W_src, b_src, W_dst, b_dst, W_self, b_self, W_lin, b_lin, attn,
        WbT, biasc, ath);
    {
        dim3 grid((NN + 63) / 64, 2);
        proj_gemm_mfma<<<grid, 256, 0, stream>>>(featb, WbT, biasc,
                                                 packs, erh, out);
    }

    // fused edge phase: one wave per node
    node_agg4<<<(NN + 3) / 4, 256, 0, stream>>>((const uint4*)packs, erh, ath,
                                                offsets, counts, srcbuck, out);
}

// Round 10
// 255.184 us; speedup vs baseline: 1.7038x; 1.0266x over previous
//
#include <hip/hip_runtime.h>
#include <hip/hip_bf16.h>

// Problem constants (from reference)
#define NN 50000
#define EE 800000
#define INF_ 128
#define HH 4
#define FF 32
#define HF 128          // H*F
#define OUTC 160        // (H+1)*F per node
#define NEG_SLOPE 0.2f

#define SCAN_B 196      // ceil(50000/256)
#define NROWS_PAD 50048 // 782*64 (GEMM reads padded A rows; OOB rows discarded)

#define PF_BLOCKS 3125  // NN*16/256 (prep_feat chunks)
#define PW_BLOCKS 208   // 416*128/256 (prep_weights)
#define PH_BLOCKS 3125  // ceil(EE/256) (hist)

typedef __attribute__((ext_vector_type(8))) short short8;
typedef __attribute__((ext_vector_type(4))) float f32x4;
typedef _Float16 f16x2 __attribute__((ext_vector_type(2)));
typedef float fl2 __attribute__((ext_vector_type(2)));

// fp32 -> bf16 bits, round-to-nearest-even
__device__ __forceinline__ unsigned short f2bf(float f) {
    union { float f; unsigned u; } in; in.f = f;
    unsigned u = in.u;
    u += 0x7fffu + ((u >> 16) & 1u);
    return (unsigned short)(u >> 16);
}
__device__ __forceinline__ unsigned short f2h(float f) {
    _Float16 h = (_Float16)f;
    return __builtin_bit_cast(unsigned short, h);
}
__device__ __forceinline__ f16x2 bch(unsigned u) {
    return __builtin_bit_cast(f16x2, u);
}
__device__ __forceinline__ f16x2 habs2(f16x2 v) {
    unsigned u = __builtin_bit_cast(unsigned, v) & 0x7FFF7FFFu;
    return __builtin_bit_cast(f16x2, u);
}

// async global->LDS 16B copy: LDS dest = wave-uniform base + lane*16
__device__ __forceinline__ void async_cp16(const void* g, void* l) {
    __builtin_amdgcn_global_load_lds(
        (const __attribute__((address_space(1))) void*)g,
        (__attribute__((address_space(3))) void*)l, 16, 0, 0);
}

// ---------------- fused prep: feat->bf16 swizzle | weights | hist ----------------
__global__ __launch_bounds__(256) void prep_all(
    const float* __restrict__ feat,
    const float* __restrict__ W0, const float* __restrict__ b0,
    const float* __restrict__ W1, const float* __restrict__ b1,
    const float* __restrict__ W2, const float* __restrict__ b2,
    const float* __restrict__ W3, const float* __restrict__ b3,
    const float* __restrict__ attn,
    const int* __restrict__ dst,
    unsigned short* __restrict__ fb, unsigned short* __restrict__ WbT,
    float* __restrict__ biasc, unsigned short* __restrict__ ath,
    int* __restrict__ counts, int* __restrict__ rank)
{
    const int b = blockIdx.x;
    const int tid = threadIdx.x;
    if (b < PF_BLOCKS) {
        // feat -> bf16, XOR-swizzled 16B chunks: chunk c of row r at c ^ (r&15)
        int idx = b * 256 + tid;
        if (idx >= NN * 16) return;
        int r = idx >> 4, c = idx & 15;
        const float4* fp = (const float4*)(feat + (size_t)r * 128 + c * 8);
        float4 v0 = fp[0], v1 = fp[1];
        uint4 o;
        o.x = (unsigned)f2bf(v0.x) | ((unsigned)f2bf(v0.y) << 16);
        o.y = (unsigned)f2bf(v0.z) | ((unsigned)f2bf(v0.w) << 16);
        o.z = (unsigned)f2bf(v1.x) | ((unsigned)f2bf(v1.y) << 16);
        o.w = (unsigned)f2bf(v1.z) | ((unsigned)f2bf(v1.w) << 16);
        *(uint4*)(fb + (size_t)r * 128 + ((c ^ (r & 15)) << 3)) = o;
    } else if (b < PF_BLOCKS + PW_BLOCKS) {
        // weights: concat + transpose + bf16, same swizzle
        int idx = (b - PF_BLOCKS) * 256 + tid;
        int n = idx >> 7, k = idx & 127;
        float v;
        if (n < 128)      v = W0[k * 128 + n];
        else if (n < 256) v = W1[k * 128 + (n - 128)];
        else if (n < 384) v = W2[k * 128 + (n - 256)];
        else              v = W3[k * 32  + (n - 384)];
        int phys = (((k >> 3) ^ (n & 15)) << 3) | (k & 7);
        WbT[n * 128 + phys] = f2bf(v);
        if (idx < 416) {
            float bv;
            if (idx < 128)      bv = b0[idx];
            else if (idx < 256) bv = b1[idx - 128];
            else if (idx < 384) bv = b2[idx - 256];
            else                bv = b3[idx - 384];
            biasc[idx] = bv;
        }
        if (idx < 128) ath[idx] = f2h(attn[idx]);
    } else {
        // histogram; atomic return value = rank within dst bucket
        int e = (b - PF_BLOCKS - PW_BLOCKS) * 256 + tid;
        if (e < EE) rank[e] = atomicAdd(&counts[dst[e]], 1);
    }
}

// ---------------- CSR scan + scatter ----------------
__global__ __launch_bounds__(256) void scan_bsum(
    const int* __restrict__ counts, int* __restrict__ bsum)
{
    __shared__ int sh[256];
    int t = threadIdx.x;
    int idx = blockIdx.x * 256 + t;
    sh[t] = (idx < NN) ? counts[idx] : 0;
    __syncthreads();
    #pragma unroll
    for (int off = 128; off > 0; off >>= 1) {
        if (t < off) sh[t] += sh[t + off];
        __syncthreads();
    }
    if (t == 0) bsum[blockIdx.x] = sh[0];
}

__global__ __launch_bounds__(256) void scan_top(
    const int* __restrict__ bsum, int* __restrict__ bprefix)
{
    __shared__ int sh[256];
    int t = threadIdx.x;
    int v = (t < SCAN_B) ? bsum[t] : 0;
    sh[t] = v;
    __syncthreads();
    #pragma unroll
    for (int off = 1; off < 256; off <<= 1) {
        int u = (t >= off) ? sh[t - off] : 0;
        __syncthreads();
        sh[t] += u;
        __syncthreads();
    }
    if (t < SCAN_B) bprefix[t] = sh[t] - v;   // exclusive
}

__global__ __launch_bounds__(256) void scan_final(
    const int* __restrict__ counts, const int* __restrict__ bprefix,
    int* __restrict__ offsets)
{
    __shared__ int sh[256];
    int t = threadIdx.x;
    int idx = blockIdx.x * 256 + t;
    int v = (idx < NN) ? counts[idx] : 0;
    sh[t] = v;
    __syncthreads();
    #pragma unroll
    for (int off = 1; off < 256; off <<= 1) {
        int u = (t >= off) ? sh[t - off] : 0;
        __syncthreads();
        sh[t] += u;
        __syncthreads();
    }
    if (idx < NN) offsets[idx] = sh[t] - v + bprefix[blockIdx.x];
}

__global__ void scatter_kernel(const int* __restrict__ src, const int* __restrict__ dst,
                               const int* __restrict__ offsets, const int* __restrict__ rank,
                               int* __restrict__ srcbuck)
{
    int e = blockIdx.x * blockDim.x + threadIdx.x;
    if (e < EE) srcbuck[offsets[dst[e]] + rank[e]] = src[e];
}

// ---------------- bf16 MFMA projection GEMM, async-staged, LDS-coalesced epilogue ----
// grid (782, 2). y=0: cols 0..207   -> muth ch 0..127 (f16) + erh ch 0..79 (f16)
//                y=1: cols 208..415 -> erh ch 80..127, selfh ch 0..127, out ch 0..31 (f32)
#define CS0 216   // y=0 LDS epilogue row stride (ushorts): %8==0, %16==8 (<=4-way)
#define CS1 184   // y=1 stride for 176 cols
__global__ __launch_bounds__(256) void proj_gemm_mfma(
    const unsigned short* __restrict__ featb,
    const unsigned short* __restrict__ WbT,
    const float* __restrict__ biasc,
    unsigned short* __restrict__ muth, unsigned short* __restrict__ selfh,
    unsigned short* __restrict__ erh, float* __restrict__ out)
{
    __shared__ __align__(16) char lds[16384 + 53248];   // As 16KB | Bs 52KB; Cs aliases
    unsigned short* As = (unsigned short*)lds;
    unsigned short* Bs = (unsigned short*)(lds + 16384);
    unsigned short* Cs = (unsigned short*)lds;           // reused post-MFMA (<=27.7KB)

    const int tid  = threadIdx.x;
    const int wv   = tid >> 6;
    const int lane = tid & 63;
    const int row0 = blockIdx.x * 64;
    const int yb   = blockIdx.y;
    const int nbase = yb * 208;

    {
        const char* g = (const char*)(featb + (size_t)row0 * 128);
        #pragma unroll
        for (int it = 0; it < 4; ++it) {
            int seg = wv * 4 + it;
            async_cp16(g + seg * 1024 + lane * 16, (char*)As + seg * 1024);
        }
    }
    {
        const char* g = (const char*)(WbT + (size_t)nbase * 128);
        #pragma unroll
        for (int it = 0; it < 13; ++it) {
            int seg = wv * 13 + it;
            async_cp16(g + seg * 1024 + lane * 16, (char*)Bs + seg * 1024);
        }
    }
    __syncthreads();

    const int m16  = lane & 15;
    const int quad = lane >> 4;

    f32x4 acc[13];
    #pragma unroll
    for (int t = 0; t < 13; ++t) acc[t] = (f32x4){0.f, 0.f, 0.f, 0.f};

    short8 afr[4];
    {
        const unsigned short* Ab = As + (wv * 16 + m16) * 128;
        #pragma unroll
        for (int ks = 0; ks < 4; ++ks)
            afr[ks] = *(const short8*)(Ab + (((ks * 4 + quad) ^ m16) << 3));
    }

    #pragma unroll
    for (int t = 0; t < 13; ++t) {
        const unsigned short* Bb = Bs + (t * 16 + m16) * 128;
        #pragma unroll
        for (int ks = 0; ks < 4; ++ks) {
            short8 bfr = *(const short8*)(Bb + (((ks * 4 + quad) ^ m16) << 3));
            acc[t] = __builtin_amdgcn_mfma_f32_16x16x32_bf16(afr[ks], bfr, acc[t], 0, 0, 0);
        }
    }

    // out tiles (y=1, t=11,12): direct fp32 stores (no LDS round-trip)
    if (yb == 1) {
        #pragma unroll
        for (int t = 11; t < 13; ++t) {
            int col = nbase + t * 16 + m16;        // 384..415
            float bb = biasc[col];
            #pragma unroll
            for (int r = 0; r < 4; ++r) {
                int grow = row0 + wv * 16 + quad * 4 + r;
                if (grow < NN) out[(size_t)grow * OUTC + (col - 384)] = acc[t][r] + bb;
            }
        }
    }

    __syncthreads();   // all MFMA reads of As/Bs done -> safe to overwrite with Cs

    const int ntile = (yb == 0) ? 13 : 11;
    const int cstr  = (yb == 0) ? CS0 : CS1;
    #pragma unroll
    for (int t = 0; t < 13; ++t) {
        if (t >= ntile) break;
        int col = nbase + t * 16 + m16;
        float bb = biasc[col];
        #pragma unroll
        for (int r = 0; r < 4; ++r) {
            int lrow = wv * 16 + quad * 4 + r;
            Cs[lrow * cstr + t * 16 + m16] = f2h(acc[t][r] + bb);
        }
    }
    __syncthreads();

    // coalesced copy-out: 16B chunks
    if (yb == 0) {
        // per row: 16 chunks muth + 10 chunks erh(ch 0..79) = 26
        for (int c = tid; c < 64 * 26; c += 256) {
            int row = c / 26, c16 = c - row * 26;
            int grow = row0 + row;
            if (grow >= NN) continue;
            uint4 v = *(const uint4*)(Cs + row * CS0 + c16 * 8);
            if (c16 < 16) *(uint4*)(muth + (size_t)grow * 128 + c16 * 8) = v;
            else          *(uint4*)(erh  + (size_t)grow * 128 + (c16 - 16) * 8) = v;
        }
    } else {
        // per row: 6 chunks erh(ch 80..127) + 16 chunks selfh = 22
        for (int c = tid; c < 64 * 22; c += 256) {
            int row = c / 22, c16 = c - row * 22;
            int grow = row0 + row;
            if (grow >= NN) continue;
            uint4 v = *(const uint4*)(Cs + row * CS1 + c16 * 8);
            if (c16 < 6) *(uint4*)(erh   + (size_t)grow * 128 + 80 + c16 * 8) = v;
            else         *(uint4*)(selfh + (size_t)grow * 128 + (c16 - 6) * 8) = v;
        }
    }
}

// ---------------- fused edge phase: one wave/node, f16 dot2, split mut/self ------
// leaky(z) = 0.6z + 0.4|z|  =>  s = 0.6*dot(at,z) + 0.4*dot(at,|z|)
__device__ __forceinline__ void edgeP(
    const uint2 m, const uint2 sf, const f16x2 er01, const f16x2 er23,
    const f16x2 at01, const f16x2 at23,
    float& l, float& a0, float& a1, float& a2, float& a3)
{
    f16x2 z01 = bch(m.x) + er01;
    f16x2 z23 = bch(m.y) + er23;
    float s1 = __builtin_amdgcn_fdot2(at01, z01, 0.f, false);
    s1 = __builtin_amdgcn_fdot2(at23, z23, s1, false);
    float s2 = __builtin_amdgcn_fdot2(at01, habs2(z01), 0.f, false);
    s2 = __builtin_amdgcn_fdot2(at23, habs2(z23), s2, false);
    float s = fmaf(0.6f, s1, 0.4f * s2);
    s += __shfl_xor(s, 1, 64);
    s += __shfl_xor(s, 2, 64);
    s += __shfl_xor(s, 4, 64);
    float p = __expf(s);
    l += p;
    fl2 c01 = __builtin_convertvector(bch(sf.x), fl2);
    fl2 c23 = __builtin_convertvector(bch(sf.y), fl2);
    a0 = fmaf(p, c01.x, a0);
    a1 = fmaf(p, c01.y, a1);
    a2 = fmaf(p, c23.x, a2);
    a3 = fmaf(p, c23.y, a3);
}

__global__ __launch_bounds__(256) void node_agg5(
    const unsigned short* __restrict__ muth,   // [N][128] f16
    const unsigned short* __restrict__ selfh,  // [N][128] f16
    const unsigned short* __restrict__ erh,    // [N][128] f16
    const unsigned short* __restrict__ ath,    // [128] f16
    const int* __restrict__ offsets, const int* __restrict__ counts,
    const int* __restrict__ srcbuck, float* __restrict__ out)
{
    const int n = blockIdx.x * 4 + (threadIdx.x >> 6);
    if (n >= NN) return;
    const int lane = threadIdx.x & 63;
    const int half = lane >> 5;          // contiguous half of the bucket
    const int li   = lane & 31;          // channel group: 4li..4li+3

    uint2 aw = *(const uint2*)(ath + li * 4);
    uint2 ew = *(const uint2*)(erh + (size_t)n * HF + li * 4);
    const f16x2 at01 = bch(aw.x), at23 = bch(aw.y);
    const f16x2 er01 = bch(ew.x), er23 = bch(ew.y);

    const int beg = offsets[n];
    const int deg = counts[n];
    const int cnt0 = (deg + 1) >> 1;
    const int st  = beg + (half ? cnt0 : 0);
    const int cnt = half ? (deg - cnt0) : cnt0;

    float l = 0.f, a0 = 0.f, a1 = 0.f, a2 = 0.f, a3 = 0.f;

    int k = 0;
    for (; k + 4 <= cnt; k += 4) {
        int i0 = srcbuck[st + k];
        int i1 = srcbuck[st + k + 1];
        int i2 = srcbuck[st + k + 2];
        int i3 = srcbuck[st + k + 3];
        uint2 m0 = *(const uint2*)(muth + (size_t)i0 * HF + li * 4);
        uint2 m1 = *(const uint2*)(muth + (size_t)i1 * HF + li * 4);
        uint2 m2 = *(const uint2*)(muth + (size_t)i2 * HF + li * 4);
        uint2 m3 = *(const uint2*)(muth + (size_t)i3 * HF + li * 4);
        uint2 s0 = *(const uint2*)(selfh + (size_t)i0 * HF + li * 4);
        uint2 s1 = *(const uint2*)(selfh + (size_t)i1 * HF + li * 4);
        uint2 s2 = *(const uint2*)(selfh + (size_t)i2 * HF + li * 4);
        uint2 s3 = *(const uint2*)(selfh + (size_t)i3 * HF + li * 4);
        edgeP(m0, s0, er01, er23, at01, at23, l, a0, a1, a2, a3);
        edgeP(m1, s1, er01, er23, at01, at23, l, a0, a1, a2, a3);
        edgeP(m2, s2, er01, er23, at01, at23, l, a0, a1, a2, a3);
        edgeP(m3, s3, er01, er23, at01, at23, l, a0, a1, a2, a3);
    }
    for (; k < cnt; ++k) {
        int i0 = srcbuck[st + k];
        uint2 m0 = *(const uint2*)(muth + (size_t)i0 * HF + li * 4);
        uint2 s0 = *(const uint2*)(selfh + (size_t)i0 * HF + li * 4);
        edgeP(m0, s0, er01, er23, at01, at23, l, a0, a1, a2, a3);
    }

    l  += __shfl_xor(l,  32, 64);
    a0 += __shfl_xor(a0, 32, 64);
    a1 += __shfl_xor(a1, 32, 64);
    a2 += __shfl_xor(a2, 32, 64);
    a3 += __shfl_xor(a3, 32, 64);

    if (half == 0) {
        float inv = (l > 0.f) ? __frcp_rn(l) : 0.f;
        float4 r = make_float4(a0 * inv, a1 * inv, a2 * inv, a3 * inv);
        *(float4*)(out + (size_t)n * OUTC + FF + li * 4) = r;
    }
}

extern "C" void kernel_launch(void* const* d_in, const int* in_sizes, int n_in,
                              void* d_out, int out_size, void* d_ws, size_t ws_size,
                              hipStream_t stream) {
    const float* feat   = (const float*)d_in[0];
    const float* W_src  = (const float*)d_in[1];
    const float* b_src  = (const float*)d_in[2];
    const float* W_dst  = (const float*)d_in[3];
    const float* b_dst  = (const float*)d_in[4];
    const float* W_self = (const float*)d_in[5];
    const float* b_self = (const float*)d_in[6];
    const float* W_lin  = (const float*)d_in[7];
    const float* b_lin  = (const float*)d_in[8];
    const float* attn   = (const float*)d_in[9];
    const int*   src    = (const int*)d_in[10];
    const int*   dst    = (const int*)d_in[11];
    float* out = (float*)d_out;

    // workspace carve-up
    unsigned short* muth  = (unsigned short*)d_ws;                  // N*128 f16
    unsigned short* selfh = muth  + (size_t)NN * HF;                // N*128 f16
    unsigned short* erh   = selfh + (size_t)NN * HF;                // N*128 f16
    unsigned short* featb = erh   + (size_t)NN * HF;                // NROWS_PAD*128 bf16
    unsigned short* WbT   = featb + (size_t)NROWS_PAD * 128;        // 416*128 bf16
    unsigned short* ath   = WbT + 416 * 128;                        // 128 f16
    float* biasc   = (float*)(ath + 128);                           // 416 fp32
    int*   counts  = (int*)(biasc + 416);
    int*   offsets = counts  + NN;
    int*   rank    = offsets + NN;                                  // E ints
    int*   srcbuck = rank    + EE;                                  // E ints
    int*   bsum    = srcbuck + EE;                                  // SCAN_B
    int*   bprefix = bsum    + SCAN_B;                              // SCAN_B

    hipMemsetAsync(counts, 0, (size_t)NN * sizeof(int), stream);

    // fused prep (feat swizzle | weights | hist)
    prep_all<<<PF_BLOCKS + PW_BLOCKS + PH_BLOCKS, 256, 0, stream>>>(
        feat, W_src, b_src, W_dst, b_dst, W_self, b_self, W_lin, b_lin, attn,
        dst, featb, WbT, biasc, ath, counts, rank);

    // CSR scan + scatter
    scan_bsum <<<SCAN_B, 256, 0, stream>>>(counts, bsum);
    scan_top  <<<1, 256, 0, stream>>>(bsum, bprefix);
    scan_final<<<SCAN_B, 256, 0, stream>>>(counts, bprefix, offsets);
    scatter_kernel<<<(EE + 255) / 256, 256, 0, stream>>>(src, dst, offsets, rank, srcbuck);

    // projection GEMM
    {
        dim3 grid((NN + 63) / 64, 2);
        proj_gemm_mfma<<<grid, 256, 0, stream>>>(featb, WbT, biasc,
                                                 muth, selfh, erh, out);
    }

    // fused edge phase: one wave per node
    node_agg5<<<(NN + 3) / 4, 256, 0, stream>>>(muth, selfh, erh, ath,
                                                offsets, counts, srcbuck, out);
}